// Round 1
// baseline (272.587 us; speedup 1.0000x reference)
//
#include <hip/hip_runtime.h>

// Hadamard transform along C of NCHW f32 tensor:
// y[b,:,s] = (H1024 @ pad1024(x[b,:,s]))[:768] / 32
// H1024 = H32 (x) H32  (Sylvester), c = 32*i + j.
//
// Block: 256 threads, 32 spatial positions (float2 per lane along s).
// Phase 1: in-register FWHT over j (rows i = 0..23; 24..31 are zero pad).
// LDS transpose (q-split in 2 rounds, 50.8KB), Phase 2: FWHT over i, store.

#define NSPAT 3136            // 56*56
#define TS    32              // spatial tile per block
#define STQ   33              // LDS q-stride (floats), odd
#define STI   529             // LDS i-stride (floats) = 16*STQ + 1, odd

static __device__ __forceinline__ float2 f2add(float2 a, float2 b) {
    return make_float2(a.x + b.x, a.y + b.y);
}
static __device__ __forceinline__ float2 f2sub(float2 a, float2 b) {
    return make_float2(a.x - b.x, a.y - b.y);
}

// one radix-2 FWHT stage of distance D on a 32-entry float2 array
#define FWHT_STAGE(arr, D)                                   \
    _Pragma("unroll")                                        \
    for (int _b = 0; _b < 32; _b += 2 * (D)) {               \
        _Pragma("unroll")                                    \
        for (int _k = 0; _k < (D); ++_k) {                   \
            float2 _t = arr[_b + _k];                        \
            arr[_b + _k]       = f2add(_t, arr[_b + _k + (D)]); \
            arr[_b + _k + (D)] = f2sub(_t, arr[_b + _k + (D)]); \
        }                                                    \
    }

#define FWHT32(arr)       \
    FWHT_STAGE(arr, 16)   \
    FWHT_STAGE(arr, 8)    \
    FWHT_STAGE(arr, 4)    \
    FWHT_STAGE(arr, 2)    \
    FWHT_STAGE(arr, 1)

__global__ __launch_bounds__(256, 2)
void hadamard_c768_kernel(const float* __restrict__ x, float* __restrict__ y) {
    __shared__ float lds[24 * STI];   // 12696 floats = 50784 B

    const int t   = threadIdx.x;
    const int s2  = t & 15;           // float2 index along s (s = 2*s2, 2*s2+1)
    const int g   = t >> 4;           // 0..15
    const int bid = blockIdx.x;
    const int b   = bid / (NSPAT / TS);   // batch
    const int s0  = (bid % (NSPAT / TS)) * TS;

    const int base = b * 768 * NSPAT + s0 + 2 * s2;
    const float* xb = x + base;
    float*       yb = y + base;

    // ---------------- Phase 1: load + FWHT over j (in registers) ----------
    // thread handles input rows i = g (always) and i = g+16 (if < 24)
    float2 a0[32], a1[32];
    #pragma unroll
    for (int j = 0; j < 32; ++j)
        a0[j] = *(const float2*)(xb + (32 * g + j) * NSPAT);
    FWHT32(a0)

    const bool twoRows = (g < 8);     // wave-uniform (t<128)
    if (twoRows) {
        #pragma unroll
        for (int j = 0; j < 32; ++j)
            a1[j] = *(const float2*)(xb + (32 * (g + 16) + j) * NSPAT);
        FWHT32(a1)
    }

    // ---------------- two rounds over q-halves through LDS -----------------
    #pragma unroll
    for (int round = 0; round < 2; ++round) {
        const int qbase = 16 * round;

        // write W[i][qbase..qbase+15][s] into LDS
        {
            float* p = lds + g * STI + 2 * s2;
            #pragma unroll
            for (int qq = 0; qq < 16; ++qq) {
                p[qq * STQ]     = a0[qbase + qq].x;
                p[qq * STQ + 1] = a0[qbase + qq].y;
            }
            if (twoRows) {
                float* p1 = lds + (g + 16) * STI + 2 * s2;
                #pragma unroll
                for (int qq = 0; qq < 16; ++qq) {
                    p1[qq * STQ]     = a1[qbase + qq].x;
                    p1[qq * STQ + 1] = a1[qbase + qq].y;
                }
            }
        }
        __syncthreads();

        // Phase 2: this thread owns q = qbase + g; FWHT over i, store
        {
            float2 w[32];
            const float* p = lds + g * STQ + 2 * s2;
            #pragma unroll
            for (int i = 0; i < 24; ++i)
                w[i] = make_float2(p[i * STI], p[i * STI + 1]);

            // stage d=16 with rows 24..31 known-zero
            #pragma unroll
            for (int i = 0; i < 8; ++i) {
                float2 tt = w[i];
                w[i]      = f2add(tt, w[i + 16]);
                w[i + 16] = f2sub(tt, w[i + 16]);
            }
            #pragma unroll
            for (int i = 8; i < 16; ++i)
                w[i + 16] = w[i];

            FWHT_STAGE(w, 8)
            FWHT_STAGE(w, 4)
            FWHT_STAGE(w, 2)
            FWHT_STAGE(w, 1)

            const int q = qbase + g;
            #pragma unroll
            for (int pp = 0; pp < 24; ++pp) {
                float2 v = w[pp];
                v.x *= 0.03125f;   // 1/sqrt(1024)
                v.y *= 0.03125f;
                *(float2*)(yb + (32 * pp + q) * NSPAT) = v;
            }
        }
        if (round == 0)
            __syncthreads();   // reads(A) done before writes(B)
    }
}

extern "C" void kernel_launch(void* const* d_in, const int* in_sizes, int n_in,
                              void* d_out, int out_size, void* d_ws, size_t ws_size,
                              hipStream_t stream) {
    const float* x = (const float*)d_in[0];
    float*       y = (float*)d_out;
    const int nblocks = 16 * (NSPAT / TS);   // 16 * 98 = 1568
    hadamard_c768_kernel<<<dim3(nblocks), dim3(256), 0, stream>>>(x, y);
}

// Round 2
// 267.743 us; speedup vs baseline: 1.0181x; 1.0181x over previous
//
#include <hip/hip_runtime.h>

// Hadamard transform along C of NCHW f32 tensor:
// y[b,:,s] = (H1024 @ pad1024(x[b,:,s]))[:768] / 32,  H1024 = H32 (x) H32, c = 32*i + j.
//
// v2: concurrency-first restructure (v1 was latency-bound at 18.7% occupancy).
// Block = 512 threads, TS = 32 spatial.
// Phase 1: one i-row per 16-lane group (g = t>>4, rows 0..23 real, 24..31 idle),
//          a[32] float2 in regs (64 VGPR), FWHT over j.
// LDS transpose (q-split, 2 rounds, 50.8 KB, odd strides -> <=2-way bank alias).
// Phase 2: 16 q x 32 scalar lanes (all 512 threads), FWHT over i with zero-fold,
//          nontemporal 4B stores (128B segments per 32 lanes).

#define NSPAT 3136            // 56*56
#define TS    32              // spatial tile per block
#define STQ   33              // LDS q-stride (floats), odd
#define STI   529             // LDS i-stride (floats) = 16*STQ + 1, odd

static __device__ __forceinline__ float2 f2add(float2 a, float2 b) {
    return make_float2(a.x + b.x, a.y + b.y);
}
static __device__ __forceinline__ float2 f2sub(float2 a, float2 b) {
    return make_float2(a.x - b.x, a.y - b.y);
}

// one radix-2 FWHT stage of distance D on a 32-entry float2 array
#define FWHT_STAGE2(arr, D)                                  \
    _Pragma("unroll")                                        \
    for (int _b = 0; _b < 32; _b += 2 * (D)) {               \
        _Pragma("unroll")                                    \
        for (int _k = 0; _k < (D); ++_k) {                   \
            float2 _t = arr[_b + _k];                        \
            arr[_b + _k]       = f2add(_t, arr[_b + _k + (D)]); \
            arr[_b + _k + (D)] = f2sub(_t, arr[_b + _k + (D)]); \
        }                                                    \
    }

#define FWHT32_2(arr)      \
    FWHT_STAGE2(arr, 16)   \
    FWHT_STAGE2(arr, 8)    \
    FWHT_STAGE2(arr, 4)    \
    FWHT_STAGE2(arr, 2)    \
    FWHT_STAGE2(arr, 1)

// scalar float FWHT stage
#define FWHT_STAGE1(arr, D)                                  \
    _Pragma("unroll")                                        \
    for (int _b = 0; _b < 32; _b += 2 * (D)) {               \
        _Pragma("unroll")                                    \
        for (int _k = 0; _k < (D); ++_k) {                   \
            float _t = arr[_b + _k];                         \
            arr[_b + _k]       = _t + arr[_b + _k + (D)];    \
            arr[_b + _k + (D)] = _t - arr[_b + _k + (D)];    \
        }                                                    \
    }

__global__ __launch_bounds__(512, 5)
void hadamard_c768_kernel(const float* __restrict__ x, float* __restrict__ y) {
    __shared__ float lds[24 * STI];   // 12696 floats = 50784 B

    const int t   = threadIdx.x;
    const int bid = blockIdx.x;
    const int b   = bid / (NSPAT / TS);
    const int s0  = (bid % (NSPAT / TS)) * TS;
    const int base = b * 768 * NSPAT + s0;   // 16*768*3136 < 2^31, int ok

    const int g  = t >> 4;            // 0..31 : i-row for phase 1
    const int ln = t & 15;            // float2 lane along s

    // ---------------- Phase 1: load + FWHT over j (rows 0..23) -------------
    float2 a[32];
    const bool active = (g < 24);     // wave-uniform: g = {4w..4w+3}
    if (active) {
        const float* xb = x + base + 2 * ln;
        #pragma unroll
        for (int j = 0; j < 32; ++j)
            a[j] = *(const float2*)(xb + (32 * g + j) * NSPAT);
        FWHT32_2(a)
    }

    const int q16 = t >> 5;           // 0..15 : q within round (phase 2)
    const int s   = t & 31;           // scalar spatial lane (phase 2)

    #pragma unroll
    for (int r = 0; r < 2; ++r) {
        // write W[i][q-half][s] into LDS
        if (active) {
            float* p = lds + g * STI + 2 * ln;
            #pragma unroll
            for (int qq = 0; qq < 16; ++qq) {
                p[qq * STQ]     = a[16 * r + qq].x;
                p[qq * STQ + 1] = a[16 * r + qq].y;
            }
        }
        __syncthreads();

        // Phase 2: thread owns q = 16r + q16, spatial s; FWHT over i, store
        {
            float w[32];
            const float* p = lds + q16 * STQ + s;
            #pragma unroll
            for (int i = 0; i < 24; ++i)
                w[i] = p[i * STI];

            // stage d=16 with rows 24..31 known-zero
            #pragma unroll
            for (int i = 0; i < 8; ++i) {
                float tt  = w[i];
                w[i]      = tt + w[i + 16];
                w[i + 16] = tt - w[i + 16];
            }
            #pragma unroll
            for (int i = 8; i < 16; ++i)
                w[i + 16] = w[i];

            FWHT_STAGE1(w, 8)
            FWHT_STAGE1(w, 4)
            FWHT_STAGE1(w, 2)
            FWHT_STAGE1(w, 1)

            const int q = 16 * r + q16;
            float* yb = y + base + s;
            #pragma unroll
            for (int pp = 0; pp < 24; ++pp)
                __builtin_nontemporal_store(w[pp] * 0.03125f,
                                            yb + (32 * pp + q) * NSPAT);
        }
        if (r == 0)
            __syncthreads();   // round-0 reads done before round-1 writes
    }
}

extern "C" void kernel_launch(void* const* d_in, const int* in_sizes, int n_in,
                              void* d_out, int out_size, void* d_ws, size_t ws_size,
                              hipStream_t stream) {
    const float* x = (const float*)d_in[0];
    float*       y = (float*)d_out;
    const int nblocks = 16 * (NSPAT / TS);   // 16 * 98 = 1568
    hadamard_c768_kernel<<<dim3(nblocks), dim3(512), 0, stream>>>(x, y);
}